// Round 1
// baseline (732.351 us; speedup 1.0000x reference)
//
#include <hip/hip_runtime.h>
#include <math.h>

// ---------------------------------------------------------------------------
// Sparse_Attn_Logic: Laplace filterbank conv -> BN -> avgpool -> two
// temporal-logic conv branches (Always/Eventually, with train-mode BN) ->
// concat -> 4x FC+relu.
//
// Structure:
//  K0 zero_stats      : zero fp64 accumulators in ws
//  K1 xstats          : Sx and lag-autocorrelations C[0..15] of x (fp64 atomics)
//  K2 prep            : Laplace filters (fp64), analytic BN1 mean/var,
//                       fused conv+BN+avgpool coefficients g18/alpha/delta
//  K3 branches        : per (b,c): conv+BN+pool -> Always/Eventually chains
//                       for BOTH branches -> maxpool(4,4) -> BN2/3 partial stats
//  K4 bn23_finalize   : BN2/BN3 alpha/delta
//  K5 final_ev        : BN apply + last Eventually + concat -> z0 (1024x768)
//  K6-8 gemm_relu     : z0@w1, z1@w2, z2@w3 (fp32 tiled)
//  K9 fc4             : z3@w4 (N=10) + relu -> out
// ---------------------------------------------------------------------------

#define B_SZ 1024
#define C_CH 32
#define L_IN 1024
#define L_CONV 1041   // 1024 + 32 - 16 + 1
#define L_POOL 520    // (1041-3)/2+1
#define L_S1 257      // (520-8)/2+1
#define L_S2 125      // (257-8)/2+1
#define L_MP 31       // (125-4)/4+1
#define L_S3 12       // (31-8)/2+1

// ---------------- K0: zero the fp64 accumulators --------------------------
__global__ void zero_stats_kernel(double* d) {
    int i = threadIdx.x;
    if (i < 160) d[i] = 0.0;   // stats_d[0..16] (idx 0..16), bn_d (idx 32..159)
}

// ---------------- K1: x statistics (Sx, C[0..15]) -------------------------
__global__ __launch_bounds__(256) void xstats_kernel(
    const float* __restrict__ x, double* __restrict__ stats)
{
    __shared__ float xr[1024];
    __shared__ float wred[4][17];
    int b = blockIdx.x, tid = threadIdx.x;
    for (int i = tid; i < 1024; i += 256) xr[i] = x[b * 1024 + i];
    __syncthreads();
    float acc[17];
#pragma unroll
    for (int d = 0; d < 17; ++d) acc[d] = 0.f;
    for (int p = tid; p < 1024; p += 256) {
        float v = xr[p];
        acc[16] += v;
#pragma unroll
        for (int d = 0; d < 16; ++d)
            if (p + d < 1024) acc[d] += v * xr[p + d];
    }
#pragma unroll
    for (int off = 32; off >= 1; off >>= 1)
#pragma unroll
        for (int d = 0; d < 17; ++d)
            acc[d] += __shfl_down(acc[d], off);
    int wave = tid >> 6, lane = tid & 63;
    if (lane == 0)
        for (int d = 0; d < 17; ++d) wred[wave][d] = acc[d];
    __syncthreads();
    if (tid < 17) {
        double tot = (double)wred[0][tid] + (double)wred[1][tid]
                   + (double)wred[2][tid] + (double)wred[3][tid];
        atomicAdd(&stats[tid], tot);
    }
}

// ---------------- K2: filters + analytic BN1 ------------------------------
__global__ __launch_bounds__(512) void prep_kernel(
    const double* __restrict__ stats,
    const float* __restrict__ la_a, const float* __restrict__ la_b,
    const float* __restrict__ bn1_g, const float* __restrict__ bn1_b,
    float* __restrict__ g18_out, float* __restrict__ a1d1_out)
{
    __shared__ float fs[32][16];
    int tid = threadIdx.x;
    if (tid < 512) {
        int c = tid >> 4, k = tid & 15;
        const double A = 0.08, ep = 0.03, tal = 0.1;
        const double w = 2.0 * 3.14159265358979323846 * 50.0;
        const double q = 1.0 - ep * ep;
        double t = (double)k / 15.0;
        double p = t - (double)la_b[c] / (double)la_a[c];
        double arg = w * (p - tal);
        double y = A * exp(-ep / sqrt(q) * arg) * (-sin(arg));
        fs[c][k] = (float)y;
    }
    __syncthreads();
    if (tid < 32) {
        int c = tid;
        // fused conv+avgpool(3,2) taps: coefficient of x at window offset i
        for (int i = 0; i < 18; ++i) {
            float g = 0.f;
            for (int k = i - 2; k <= i; ++k)
                if (k >= 0 && k < 16) g += fs[c][k];
            g18_out[c * 18 + i] = g;
        }
        double Sf = 0.0;
        for (int k = 0; k < 16; ++k) Sf += (double)fs[c][k];
        double E2 = 0.0;
        for (int k = 0; k < 16; ++k)
            for (int k2 = 0; k2 < 16; ++k2)
                E2 += (double)fs[c][k] * (double)fs[c][k2]
                    * stats[k > k2 ? k - k2 : k2 - k];
        const double N = 1024.0 * 1041.0;
        double Sx = stats[16];
        double mc  = Sx * Sf / N;          // mean of conv (pre-bias)
        double var = E2 / N - mc * mc;     // bias cancels in variance
        double invstd = 1.0 / sqrt(var + 1e-5);
        float alpha = bn1_g[c] * (float)invstd;
        a1d1_out[c]      = alpha / 3.0f;                     // folds avgpool /3
        a1d1_out[32 + c] = bn1_b[c] - (float)mc * alpha;     // la_bias cancels
    }
}

// ---------------- K3: fused conv+BN+pool + both branches ------------------
__global__ __launch_bounds__(64) void branches_kernel(
    const float* __restrict__ x,
    const float* __restrict__ g18g, const float* __restrict__ a1d1,
    const float* __restrict__ a1w_g, const float* __restrict__ a1b_g,
    const float* __restrict__ e1w_g, const float* __restrict__ e1b_g,
    const float* __restrict__ f1w_g, const float* __restrict__ f1b_g,
    const float* __restrict__ faw_g, const float* __restrict__ fab_g,
    float* __restrict__ p1, float* __restrict__ p2,
    double* __restrict__ bn_d)
{
    __shared__ float xr[1056];            // 16 zero-pad each side
    __shared__ float hr[L_POOL];
    __shared__ float x1[L_S1], x2[L_S1];
    __shared__ float y1[L_S2], y2[L_S2];
    __shared__ float g18[18];
    __shared__ float wts[32];             // a1w | e1w | f1w | faw
    int bc = blockIdx.x, b = bc >> 5, c = bc & 31, t = threadIdx.x;

    for (int i = t; i < 1056; i += 64) {
        float v = 0.f;
        if (i >= 16 && i < 1040) v = x[b * 1024 + (i - 16)];
        xr[i] = v;
    }
    if (t < 18) g18[t] = g18g[c * 18 + t];
    if (t < 8) {
        wts[t]      = a1w_g[c * 8 + t];
        wts[8 + t]  = e1w_g[c * 8 + t];
        wts[16 + t] = f1w_g[c * 8 + t];
        wts[24 + t] = faw_g[c * 8 + t];
    }
    float alpha = a1d1[c], delta = a1d1[32 + c];
    __syncthreads();

    // conv + BN1 + avgpool -> hr[520]
    for (int j = t; j < L_POOL; j += 64) {
        float s = 0.f;
#pragma unroll
        for (int i = 0; i < 18; ++i) s += g18[i] * xr[2 * j + i];
        hr[j] = s * alpha + delta;
    }
    __syncthreads();

    float A1 = a1b_g[c], E1 = 1.f - e1b_g[c], F1 = 1.f - f1b_g[c], FA = fab_g[c];
#pragma unroll
    for (int k = 0; k < 8; ++k) { A1 -= wts[k]; FA -= wts[24 + k]; }

    // stage 1: branch1 Always(a1), branch2 Eventually(f1)  (leaky(relu)=relu)
    for (int n = t; n < L_S1; n += 64) {
        float s1 = 0.f, s2 = 0.f;
#pragma unroll
        for (int k = 0; k < 8; ++k) {
            float h = hr[2 * n + k];
            s1 += h * wts[k];
            s2 += h * wts[16 + k];
        }
        float v1 = A1 + s1; x1[n] = v1 > 0.f ? v1 : 0.f;
        float v2 = F1 + s2; x2[n] = v2 > 0.f ? v2 : 0.f;
    }
    __syncthreads();

    // stage 2: branch1 Eventually(e1), branch2 Always(fa)
    for (int m = t; m < L_S2; m += 64) {
        float s1 = 0.f, s2 = 0.f;
#pragma unroll
        for (int k = 0; k < 8; ++k) {
            s1 += x1[2 * m + k] * wts[8 + k];
            s2 += x2[2 * m + k] * wts[24 + k];
        }
        float v1 = E1 + s1; y1[m] = v1 > 0.f ? v1 : 0.f;
        float v2 = FA + s2; y2[m] = v2 > 0.f ? v2 : 0.f;
    }
    __syncthreads();

    // maxpool(4,4) + BN2/3 partial stats
    float s1 = 0.f, q1 = 0.f, s2 = 0.f, q2 = 0.f;
    if (t < L_MP) {
        float v1 = y1[4 * t], v2 = y2[4 * t];
#pragma unroll
        for (int k = 1; k < 4; ++k) {
            v1 = fmaxf(v1, y1[4 * t + k]);
            v2 = fmaxf(v2, y2[4 * t + k]);
        }
        p1[bc * L_MP + t] = v1;
        p2[bc * L_MP + t] = v2;
        s1 = v1; q1 = v1 * v1; s2 = v2; q2 = v2 * v2;
    }
#pragma unroll
    for (int off = 32; off >= 1; off >>= 1) {
        s1 += __shfl_down(s1, off);
        q1 += __shfl_down(q1, off);
        s2 += __shfl_down(s2, off);
        q2 += __shfl_down(q2, off);
    }
    if (t == 0) {
        atomicAdd(&bn_d[c],      (double)s1);
        atomicAdd(&bn_d[32 + c], (double)q1);
        atomicAdd(&bn_d[64 + c], (double)s2);
        atomicAdd(&bn_d[96 + c], (double)q2);
    }
}

// ---------------- K4: finalize BN2 / BN3 ----------------------------------
__global__ void bn23_finalize_kernel(
    const double* __restrict__ bn_d,
    const float* __restrict__ bn2_g, const float* __restrict__ bn2_b,
    const float* __restrict__ bn3_g, const float* __restrict__ bn3_b,
    float* __restrict__ ad23)
{
    int t = threadIdx.x;
    if (t < 64) {
        int br = t >> 5, c = t & 31;
        double sum = bn_d[br * 64 + c], sq = bn_d[br * 64 + 32 + c];
        const double N = 1024.0 * 31.0;
        double mean = sum / N;
        double var = sq / N - mean * mean;
        float g  = br ? bn3_g[c] : bn2_g[c];
        float be = br ? bn3_b[c] : bn2_b[c];
        float alpha = g * (float)(1.0 / sqrt(var + 1e-5));
        ad23[br * 64 + c]      = alpha;
        ad23[br * 64 + 32 + c] = be - (float)mean * alpha;
    }
}

// ---------------- K5: BN apply + last Eventually + concat -----------------
__global__ __launch_bounds__(256) void final_ev_kernel(
    const float* __restrict__ p1, const float* __restrict__ p2,
    const float* __restrict__ e2w_g, const float* __restrict__ e2b_g,
    const float* __restrict__ f2w_g, const float* __restrict__ f2b_g,
    const float* __restrict__ ad23, float* __restrict__ z0)
{
    __shared__ float pr[2][32][31];
    __shared__ float w2s[2][32][8];
    __shared__ float al[2][32], de[2][32], eb[2][32];
    int b = blockIdx.x, tid = threadIdx.x;
    for (int i = tid; i < 992; i += 256) {
        pr[0][0][i] = p1[b * 992 + i];
        pr[1][0][i] = p2[b * 992 + i];
    }
    if (tid < 256) {
        w2s[0][0][tid] = e2w_g[tid];
        w2s[1][0][tid] = f2w_g[tid];
    }
    if (tid < 32) {
        al[0][tid] = ad23[tid];      de[0][tid] = ad23[32 + tid];
        al[1][tid] = ad23[64 + tid]; de[1][tid] = ad23[96 + tid];
        eb[0][tid] = e2b_g[tid];     eb[1][tid] = f2b_g[tid];
    }
    __syncthreads();
    for (int u = tid; u < 768; u += 256) {
        int br = u / 384, rem = u - br * 384;
        int c = rem / 12, tt = rem - c * 12;
        float a = al[br][c], d = de[br][c];
        float s = 1.f - eb[br][c];
#pragma unroll
        for (int k = 0; k < 8; ++k)
            s += (pr[br][c][2 * tt + k] * a + d) * w2s[br][c][k];
        z0[b * 768 + u] = s > 0.f ? s : 0.f;
    }
}

// ---------------- K6-8: fp32 tiled GEMM + bias + relu ---------------------
// C[M,N] = relu(A[M,K] @ B[K,N] + bias[N]); M,N mult of 64, K mult of 16.
__global__ __launch_bounds__(256) void gemm_relu_kernel(
    const float* __restrict__ A, const float* __restrict__ B,
    const float* __restrict__ bias, float* __restrict__ C,
    int M, int N, int K)
{
    __shared__ float As[16][65];
    __shared__ float Bs[16][65];
    int tid = threadIdx.x;
    int tx = tid & 15, ty = tid >> 4;
    int m0 = blockIdx.y * 64, n0 = blockIdx.x * 64;
    float acc[4][4] = {};
    for (int k0 = 0; k0 < K; k0 += 16) {
        for (int i = tid; i < 64 * 16; i += 256) {
            int r = i >> 4, c = i & 15;
            As[c][r] = A[(m0 + r) * K + k0 + c];
        }
        for (int i = tid; i < 16 * 64; i += 256) {
            int r = i >> 6, c = i & 63;
            Bs[r][c] = B[(k0 + r) * N + n0 + c];
        }
        __syncthreads();
#pragma unroll
        for (int kk = 0; kk < 16; ++kk) {
            float a[4], bb[4];
#pragma unroll
            for (int i = 0; i < 4; ++i) a[i] = As[kk][ty * 4 + i];
#pragma unroll
            for (int j = 0; j < 4; ++j) bb[j] = Bs[kk][tx * 4 + j];
#pragma unroll
            for (int i = 0; i < 4; ++i)
#pragma unroll
                for (int j = 0; j < 4; ++j)
                    acc[i][j] += a[i] * bb[j];
        }
        __syncthreads();
    }
#pragma unroll
    for (int i = 0; i < 4; ++i) {
        int m = m0 + ty * 4 + i;
#pragma unroll
        for (int j = 0; j < 4; ++j) {
            int n = n0 + tx * 4 + j;
            float v = acc[i][j] + bias[n];
            C[m * N + n] = v > 0.f ? v : 0.f;
        }
    }
}

// ---------------- K9: last FC (N=10) --------------------------------------
__global__ __launch_bounds__(256) void fc4_kernel(
    const float* __restrict__ z3, const float* __restrict__ w4,
    const float* __restrict__ b4, float* __restrict__ out)
{
    int g = blockIdx.x * 256 + threadIdx.x;
    if (g >= 1024 * 10) return;
    int m = g / 10, n = g - m * 10;
    float acc = b4[n];
#pragma unroll 8
    for (int k = 0; k < 128; ++k)
        acc += z3[m * 128 + k] * w4[k * 10 + n];
    out[g] = acc > 0.f ? acc : 0.f;
}

// ---------------------------------------------------------------------------
extern "C" void kernel_launch(void* const* d_in, const int* in_sizes, int n_in,
                              void* d_out, int out_size, void* d_ws, size_t ws_size,
                              hipStream_t stream)
{
    (void)in_sizes; (void)n_in; (void)out_size; (void)ws_size;
    const float* x      = (const float*)d_in[0];
    const float* la_a   = (const float*)d_in[1];
    const float* la_b   = (const float*)d_in[2];
    // d_in[3] la_bias: cancels analytically in BN1 (affine before train-mode BN)
    const float* bn1_g  = (const float*)d_in[4];
    const float* bn1_b  = (const float*)d_in[5];
    const float* a1_w   = (const float*)d_in[6];
    const float* a1_b   = (const float*)d_in[7];
    const float* e1_w   = (const float*)d_in[8];
    const float* e1_b   = (const float*)d_in[9];
    const float* bn2_g  = (const float*)d_in[10];
    const float* bn2_b  = (const float*)d_in[11];
    const float* e2_w   = (const float*)d_in[12];
    const float* e2_b   = (const float*)d_in[13];
    const float* f1_w   = (const float*)d_in[14];
    const float* f1_b   = (const float*)d_in[15];
    const float* fa_w   = (const float*)d_in[16];
    const float* fa_b   = (const float*)d_in[17];
    const float* bn3_g  = (const float*)d_in[18];
    const float* bn3_b  = (const float*)d_in[19];
    const float* f2_w   = (const float*)d_in[20];
    const float* f2_b   = (const float*)d_in[21];
    const float* w1     = (const float*)d_in[22];
    const float* b1     = (const float*)d_in[23];
    const float* w2     = (const float*)d_in[24];
    const float* b2     = (const float*)d_in[25];
    const float* w3     = (const float*)d_in[26];
    const float* b3     = (const float*)d_in[27];
    const float* w4     = (const float*)d_in[28];
    const float* b4     = (const float*)d_in[29];
    float* out = (float*)d_out;

    char* w = (char*)d_ws;
    double* stats_d = (double*)(w + 0);        // 17 doubles
    double* bn_d    = (double*)(w + 256);      // 128 doubles (idx 32..159)
    float* g18      = (float*)(w + 1536);      // 32*18
    float* a1d1     = (float*)(w + 3840);      // 64
    float* ad23     = (float*)(w + 4096);      // 128
    float* p1       = (float*)(w + 8192);                 // 1024*32*31
    float* p2       = (float*)(w + 8192 + 4063232);       // 4071424
    float* z0       = (float*)(w + 8134656);              // 1024*768
    float* z1       = (float*)(w + 11280384);             // 1024*1024
    float* z2       = (float*)(w + 15474688);             // 1024*512
    float* z3       = (float*)(w + 17571840);             // 1024*128
    // total ws use: ~18.1 MB

    zero_stats_kernel<<<1, 256, 0, stream>>>(stats_d);
    xstats_kernel<<<1024, 256, 0, stream>>>(x, stats_d);
    prep_kernel<<<1, 512, 0, stream>>>(stats_d, la_a, la_b, bn1_g, bn1_b, g18, a1d1);
    branches_kernel<<<1024 * 32, 64, 0, stream>>>(
        x, g18, a1d1, a1_w, a1_b, e1_w, e1_b, f1_w, f1_b, fa_w, fa_b,
        p1, p2, bn_d);
    bn23_finalize_kernel<<<1, 64, 0, stream>>>(bn_d, bn2_g, bn2_b, bn3_g, bn3_b, ad23);
    final_ev_kernel<<<1024, 256, 0, stream>>>(p1, p2, e2_w, e2_b, f2_w, f2_b, ad23, z0);
    gemm_relu_kernel<<<dim3(16, 16), 256, 0, stream>>>(z0, w1, b1, z1, 1024, 1024, 768);
    gemm_relu_kernel<<<dim3(8, 16), 256, 0, stream>>>(z1, w2, b2, z2, 1024, 512, 1024);
    gemm_relu_kernel<<<dim3(2, 16), 256, 0, stream>>>(z2, w3, b3, z3, 1024, 128, 512);
    fc4_kernel<<<40, 256, 0, stream>>>(z3, w4, b4, out);
}

// Round 2
// 484.916 us; speedup vs baseline: 1.5103x; 1.5103x over previous
//
#include <hip/hip_runtime.h>
#include <math.h>

// ---------------------------------------------------------------------------
// Sparse_Attn_Logic — round 2.
// R1 evidence: branches_kernel 210us, VALUBusy 20%, occupancy 37% -> latency
// bound. GEMM1 ran at 1 block/CU. This round: branches = 1 block per b
// (8 waves, shared x, per-wave LDS scratch, 3 blocks/CU); GEMM = 32x32 tiles,
// 64 thr, 4x4 micro, 1024/512/128 blocks.
// ---------------------------------------------------------------------------

#define B_SZ 1024
#define C_CH 32
#define L_POOL 520
#define L_S1 257
#define L_S2 125
#define L_MP 31

// ---------------- K0: zero the fp64 accumulators --------------------------
__global__ void zero_stats_kernel(double* d) {
    int i = threadIdx.x;
    if (i < 160) d[i] = 0.0;
}

// ---------------- K1: x statistics (Sx, C[0..15]) -------------------------
__global__ __launch_bounds__(256) void xstats_kernel(
    const float* __restrict__ x, double* __restrict__ stats)
{
    __shared__ float xr[1024];
    __shared__ float wred[4][17];
    int b = blockIdx.x, tid = threadIdx.x;
    for (int i = tid; i < 1024; i += 256) xr[i] = x[b * 1024 + i];
    __syncthreads();
    float acc[17];
#pragma unroll
    for (int d = 0; d < 17; ++d) acc[d] = 0.f;
    for (int p = tid; p < 1024; p += 256) {
        float v = xr[p];
        acc[16] += v;
#pragma unroll
        for (int d = 0; d < 16; ++d)
            if (p + d < 1024) acc[d] += v * xr[p + d];
    }
#pragma unroll
    for (int off = 32; off >= 1; off >>= 1)
#pragma unroll
        for (int d = 0; d < 17; ++d)
            acc[d] += __shfl_down(acc[d], off);
    int wave = tid >> 6, lane = tid & 63;
    if (lane == 0)
        for (int d = 0; d < 17; ++d) wred[wave][d] = acc[d];
    __syncthreads();
    if (tid < 17) {
        double tot = (double)wred[0][tid] + (double)wred[1][tid]
                   + (double)wred[2][tid] + (double)wred[3][tid];
        atomicAdd(&stats[tid], tot);
    }
}

// ---------------- K2: filters + analytic BN1 ------------------------------
__global__ __launch_bounds__(512) void prep_kernel(
    const double* __restrict__ stats,
    const float* __restrict__ la_a, const float* __restrict__ la_b,
    const float* __restrict__ bn1_g, const float* __restrict__ bn1_b,
    float* __restrict__ g18_out, float* __restrict__ a1d1_out)
{
    __shared__ float fs[32][16];
    int tid = threadIdx.x;
    if (tid < 512) {
        int c = tid >> 4, k = tid & 15;
        const double A = 0.08, ep = 0.03, tal = 0.1;
        const double w = 2.0 * 3.14159265358979323846 * 50.0;
        const double q = 1.0 - ep * ep;
        double t = (double)k / 15.0;
        double p = t - (double)la_b[c] / (double)la_a[c];
        double arg = w * (p - tal);
        double y = A * exp(-ep / sqrt(q) * arg) * (-sin(arg));
        fs[c][k] = (float)y;
    }
    __syncthreads();
    if (tid < 32) {
        int c = tid;
        for (int i = 0; i < 18; ++i) {
            float g = 0.f;
            for (int k = i - 2; k <= i; ++k)
                if (k >= 0 && k < 16) g += fs[c][k];
            g18_out[c * 18 + i] = g;
        }
        double Sf = 0.0;
        for (int k = 0; k < 16; ++k) Sf += (double)fs[c][k];
        double E2 = 0.0;
        for (int k = 0; k < 16; ++k)
            for (int k2 = 0; k2 < 16; ++k2)
                E2 += (double)fs[c][k] * (double)fs[c][k2]
                    * stats[k > k2 ? k - k2 : k2 - k];
        const double N = 1024.0 * 1041.0;
        double Sx = stats[16];
        double mc  = Sx * Sf / N;
        double var = E2 / N - mc * mc;
        double invstd = 1.0 / sqrt(var + 1e-5);
        float alpha = bn1_g[c] * (float)invstd;
        a1d1_out[c]      = alpha / 3.0f;
        a1d1_out[32 + c] = bn1_b[c] - (float)mc * alpha;
    }
}

// ---------------- K3: fused conv+BN+pool + both branches ------------------
// One block per batch element b. 512 threads = 8 waves; wave w handles
// channels w, w+8, w+16, w+24 in its private LDS scratch strip. x row is
// loaded once per block (was 32x redundant in R1).
#define SCR_ROW 1296   // hr[0..519] | x1 @520 (257) | x2 @780 (257) | y1 @1040 (125) | y2 @1168 (125)
__global__ __launch_bounds__(512) void branches_kernel(
    const float* __restrict__ x,
    const float* __restrict__ g18g, const float* __restrict__ a1d1,
    const float* __restrict__ a1w_g, const float* __restrict__ a1b_g,
    const float* __restrict__ e1w_g, const float* __restrict__ e1b_g,
    const float* __restrict__ f1w_g, const float* __restrict__ f1b_g,
    const float* __restrict__ faw_g, const float* __restrict__ fab_g,
    float* __restrict__ p1, float* __restrict__ p2,
    double* __restrict__ bn_d)
{
    __shared__ float xr[1060];            // 16 zero-pad front, 1024 data, pad tail
    __shared__ float scr[8][SCR_ROW];     // per-wave scratch
    __shared__ float g18s[32][18];
    __shared__ float wts[4][32][8];       // 0=a1w 1=e1w 2=f1w 3=faw

    int b = blockIdx.x, t = threadIdx.x;
    int wv = t >> 6, lane = t & 63;

    {
        float2 v = ((const float2*)(x + b * 1024))[t];
        xr[16 + 2 * t] = v.x;
        xr[17 + 2 * t] = v.y;
        if (t < 16) xr[t] = 0.f;
        if (t < 20) xr[1040 + t] = 0.f;
    }
    if (t < 288) { ((float2*)&g18s[0][0])[t] = ((const float2*)g18g)[t]; }
    if (t < 256) {
        wts[0][0][t] = a1w_g[t];
        wts[1][0][t] = e1w_g[t];
        wts[2][0][t] = f1w_g[t];
        wts[3][0][t] = faw_g[t];
    }
    __syncthreads();

    float* hr  = scr[wv];
    float* x1s = scr[wv] + 520;
    float* x2s = scr[wv] + 780;
    float* y1s = scr[wv] + 1040;
    float* y2s = scr[wv] + 1168;

    for (int cc = 0; cc < 4; ++cc) {
        int c = (cc << 3) + wv;
        float alpha = a1d1[c], delta = a1d1[32 + c];

        // conv+BN1+avgpool: 9 consecutive outputs per lane (register reuse of
        // the overlapping 18-tap windows)
        int j0 = lane * 9;
        if (j0 < L_POOL) {
            float g[18];
#pragma unroll
            for (int i = 0; i < 18; ++i) g[i] = g18s[c][i];
#pragma unroll
            for (int jj = 0; jj < 9; ++jj) {
                int j = j0 + jj;
                float s = 0.f;
#pragma unroll
                for (int i = 0; i < 18; ++i) s += g[i] * xr[2 * j + i];
                if (j < L_POOL) hr[j] = s * alpha + delta;
            }
        }
        __syncthreads();

        float A1 = a1b_g[c], F1 = 1.f - f1b_g[c];
        float wa[8], we[8], wf[8], wfa[8];
#pragma unroll
        for (int k = 0; k < 8; ++k) {
            wa[k] = wts[0][c][k]; we[k] = wts[1][c][k];
            wf[k] = wts[2][c][k]; wfa[k] = wts[3][c][k];
            A1 -= wa[k];
        }
        float E1 = 1.f - e1b_g[c], FA = fab_g[c];
#pragma unroll
        for (int k = 0; k < 8; ++k) FA -= wfa[k];

        // stage 1: branch1 Always(a1), branch2 Eventually(f1)
        for (int n = lane; n < L_S1; n += 64) {
            float s1 = 0.f, s2 = 0.f;
#pragma unroll
            for (int k = 0; k < 8; ++k) {
                float h = hr[2 * n + k];
                s1 += h * wa[k];
                s2 += h * wf[k];
            }
            float v1 = A1 + s1; x1s[n] = v1 > 0.f ? v1 : 0.f;
            float v2 = F1 + s2; x2s[n] = v2 > 0.f ? v2 : 0.f;
        }
        __syncthreads();

        // stage 2: branch1 Eventually(e1), branch2 Always(fa)
        for (int m = lane; m < L_S2; m += 64) {
            float s1 = 0.f, s2 = 0.f;
#pragma unroll
            for (int k = 0; k < 8; ++k) {
                s1 += x1s[2 * m + k] * we[k];
                s2 += x2s[2 * m + k] * wfa[k];
            }
            float v1 = E1 + s1; y1s[m] = v1 > 0.f ? v1 : 0.f;
            float v2 = FA + s2; y2s[m] = v2 > 0.f ? v2 : 0.f;
        }
        __syncthreads();

        // maxpool(4,4) + BN2/3 partial stats
        float s1 = 0.f, q1 = 0.f, s2 = 0.f, q2 = 0.f;
        if (lane < L_MP) {
            float v1 = y1s[4 * lane], v2 = y2s[4 * lane];
#pragma unroll
            for (int k = 1; k < 4; ++k) {
                v1 = fmaxf(v1, y1s[4 * lane + k]);
                v2 = fmaxf(v2, y2s[4 * lane + k]);
            }
            int bc = b * 32 + c;
            p1[bc * L_MP + lane] = v1;
            p2[bc * L_MP + lane] = v2;
            s1 = v1; q1 = v1 * v1; s2 = v2; q2 = v2 * v2;
        }
#pragma unroll
        for (int off = 32; off >= 1; off >>= 1) {
            s1 += __shfl_down(s1, off);
            q1 += __shfl_down(q1, off);
            s2 += __shfl_down(s2, off);
            q2 += __shfl_down(q2, off);
        }
        if (lane == 0) {
            atomicAdd(&bn_d[c],      (double)s1);
            atomicAdd(&bn_d[32 + c], (double)q1);
            atomicAdd(&bn_d[64 + c], (double)s2);
            atomicAdd(&bn_d[96 + c], (double)q2);
        }
        __syncthreads();
    }
}

// ---------------- K4: finalize BN2 / BN3 ----------------------------------
__global__ void bn23_finalize_kernel(
    const double* __restrict__ bn_d,
    const float* __restrict__ bn2_g, const float* __restrict__ bn2_b,
    const float* __restrict__ bn3_g, const float* __restrict__ bn3_b,
    float* __restrict__ ad23)
{
    int t = threadIdx.x;
    if (t < 64) {
        int br = t >> 5, c = t & 31;
        double sum = bn_d[br * 64 + c], sq = bn_d[br * 64 + 32 + c];
        const double N = 1024.0 * 31.0;
        double mean = sum / N;
        double var = sq / N - mean * mean;
        float g  = br ? bn3_g[c] : bn2_g[c];
        float be = br ? bn3_b[c] : bn2_b[c];
        float alpha = g * (float)(1.0 / sqrt(var + 1e-5));
        ad23[br * 64 + c]      = alpha;
        ad23[br * 64 + 32 + c] = be - (float)mean * alpha;
    }
}

// ---------------- K5: BN apply + last Eventually + concat -----------------
__global__ __launch_bounds__(256) void final_ev_kernel(
    const float* __restrict__ p1, const float* __restrict__ p2,
    const float* __restrict__ e2w_g, const float* __restrict__ e2b_g,
    const float* __restrict__ f2w_g, const float* __restrict__ f2b_g,
    const float* __restrict__ ad23, float* __restrict__ z0)
{
    __shared__ float pr[2][32][31];
    __shared__ float w2s[2][32][8];
    __shared__ float al[2][32], de[2][32], eb[2][32];
    int b = blockIdx.x, tid = threadIdx.x;
    for (int i = tid; i < 992; i += 256) {
        pr[0][0][i] = p1[b * 992 + i];
        pr[1][0][i] = p2[b * 992 + i];
    }
    if (tid < 256) {
        w2s[0][0][tid] = e2w_g[tid];
        w2s[1][0][tid] = f2w_g[tid];
    }
    if (tid < 32) {
        al[0][tid] = ad23[tid];      de[0][tid] = ad23[32 + tid];
        al[1][tid] = ad23[64 + tid]; de[1][tid] = ad23[96 + tid];
        eb[0][tid] = e2b_g[tid];     eb[1][tid] = f2b_g[tid];
    }
    __syncthreads();
    for (int u = tid; u < 768; u += 256) {
        int br = u / 384, rem = u - br * 384;
        int c = rem / 12, tt = rem - c * 12;
        float a = al[br][c], d = de[br][c];
        float s = 1.f - eb[br][c];
#pragma unroll
        for (int k = 0; k < 8; ++k)
            s += (pr[br][c][2 * tt + k] * a + d) * w2s[br][c][k];
        z0[b * 768 + u] = s > 0.f ? s : 0.f;
    }
}

// ---------------- K6-8: fp32 GEMM 32x32 tile, 64 thr, 4x4 micro -----------
// C[M,N] = relu(A[M,K] @ B[K,N] + bias[N]); M,N mult of 32, K mult of 16.
// R1 lesson: 64x64/256thr gave only 256 blocks for GEMM1 (1 block/CU).
__global__ __launch_bounds__(64) void gemm_relu_kernel(
    const float* __restrict__ A, const float* __restrict__ B,
    const float* __restrict__ bias, float* __restrict__ C,
    int M, int N, int K)
{
    __shared__ float As[16][36];   // transposed: As[k][m]
    __shared__ float Bs[16][36];   // natural:    Bs[k][n]
    int tid = threadIdx.x;
    int tx = tid & 7, ty = tid >> 3;
    int m0 = blockIdx.y * 32, n0 = blockIdx.x * 32;
    float acc[4][4] = {};
    for (int k0 = 0; k0 < K; k0 += 16) {
#pragma unroll
        for (int v = 0; v < 2; ++v) {
            int q = tid + v * 64;                 // 0..127 float4 chunks
            int ar = q >> 2, ak = (q & 3) << 2;   // A: row 0..31, k 0/4/8/12
            float4 a = *(const float4*)&A[(size_t)(m0 + ar) * K + k0 + ak];
            As[ak + 0][ar] = a.x; As[ak + 1][ar] = a.y;
            As[ak + 2][ar] = a.z; As[ak + 3][ar] = a.w;
            int br = q >> 3, bc = (q & 7) << 2;   // B: k 0..15, col 0..28
            float4 bb = *(const float4*)&B[(size_t)(k0 + br) * N + n0 + bc];
            *(float4*)&Bs[br][bc] = bb;
        }
        __syncthreads();
#pragma unroll
        for (int kk = 0; kk < 16; ++kk) {
            float a[4], bb[4];
#pragma unroll
            for (int i = 0; i < 4; ++i) a[i] = As[kk][ty * 4 + i];
#pragma unroll
            for (int j = 0; j < 4; ++j) bb[j] = Bs[kk][tx * 4 + j];
#pragma unroll
            for (int i = 0; i < 4; ++i)
#pragma unroll
                for (int j = 0; j < 4; ++j)
                    acc[i][j] += a[i] * bb[j];
        }
        __syncthreads();
    }
#pragma unroll
    for (int i = 0; i < 4; ++i) {
        int m = m0 + ty * 4 + i;
#pragma unroll
        for (int j = 0; j < 4; ++j) {
            int n = n0 + tx * 4 + j;
            float v = acc[i][j] + bias[n];
            C[(size_t)m * N + n] = v > 0.f ? v : 0.f;
        }
    }
}

// ---------------- K9: last FC (N=10) --------------------------------------
__global__ __launch_bounds__(256) void fc4_kernel(
    const float* __restrict__ z3, const float* __restrict__ w4,
    const float* __restrict__ b4, float* __restrict__ out)
{
    int g = blockIdx.x * 256 + threadIdx.x;
    if (g >= 1024 * 10) return;
    int m = g / 10, n = g - m * 10;
    float acc = b4[n];
#pragma unroll 8
    for (int k = 0; k < 128; ++k)
        acc += z3[m * 128 + k] * w4[k * 10 + n];
    out[g] = acc > 0.f ? acc : 0.f;
}

// ---------------------------------------------------------------------------
extern "C" void kernel_launch(void* const* d_in, const int* in_sizes, int n_in,
                              void* d_out, int out_size, void* d_ws, size_t ws_size,
                              hipStream_t stream)
{
    (void)in_sizes; (void)n_in; (void)out_size; (void)ws_size;
    const float* x      = (const float*)d_in[0];
    const float* la_a   = (const float*)d_in[1];
    const float* la_b   = (const float*)d_in[2];
    const float* bn1_g  = (const float*)d_in[4];
    const float* bn1_b  = (const float*)d_in[5];
    const float* a1_w   = (const float*)d_in[6];
    const float* a1_b   = (const float*)d_in[7];
    const float* e1_w   = (const float*)d_in[8];
    const float* e1_b   = (const float*)d_in[9];
    const float* bn2_g  = (const float*)d_in[10];
    const float* bn2_b  = (const float*)d_in[11];
    const float* e2_w   = (const float*)d_in[12];
    const float* e2_b   = (const float*)d_in[13];
    const float* f1_w   = (const float*)d_in[14];
    const float* f1_b   = (const float*)d_in[15];
    const float* fa_w   = (const float*)d_in[16];
    const float* fa_b   = (const float*)d_in[17];
    const float* bn3_g  = (const float*)d_in[18];
    const float* bn3_b  = (const float*)d_in[19];
    const float* f2_w   = (const float*)d_in[20];
    const float* f2_b   = (const float*)d_in[21];
    const float* w1     = (const float*)d_in[22];
    const float* b1     = (const float*)d_in[23];
    const float* w2     = (const float*)d_in[24];
    const float* b2     = (const float*)d_in[25];
    const float* w3     = (const float*)d_in[26];
    const float* b3     = (const float*)d_in[27];
    const float* w4     = (const float*)d_in[28];
    const float* b4     = (const float*)d_in[29];
    float* out = (float*)d_out;

    char* w = (char*)d_ws;
    double* stats_d = (double*)(w + 0);        // 17 doubles
    double* bn_d    = (double*)(w + 256);      // 128 doubles
    float* g18      = (float*)(w + 1536);
    float* a1d1     = (float*)(w + 3840);
    float* ad23     = (float*)(w + 4096);
    float* p1       = (float*)(w + 8192);
    float* p2       = (float*)(w + 8192 + 4063232);
    float* z0       = (float*)(w + 8134656);
    float* z1       = (float*)(w + 11280384);
    float* z2       = (float*)(w + 15474688);
    float* z3       = (float*)(w + 17571840);

    zero_stats_kernel<<<1, 256, 0, stream>>>(stats_d);
    xstats_kernel<<<1024, 256, 0, stream>>>(x, stats_d);
    prep_kernel<<<1, 512, 0, stream>>>(stats_d, la_a, la_b, bn1_g, bn1_b, g18, a1d1);
    branches_kernel<<<1024, 512, 0, stream>>>(
        x, g18, a1d1, a1_w, a1_b, e1_w, e1_b, f1_w, f1_b, fa_w, fa_b,
        p1, p2, bn_d);
    bn23_finalize_kernel<<<1, 64, 0, stream>>>(bn_d, bn2_g, bn2_b, bn3_g, bn3_b, ad23);
    final_ev_kernel<<<1024, 256, 0, stream>>>(p1, p2, e2_w, e2_b, f2_w, f2_b, ad23, z0);
    gemm_relu_kernel<<<dim3(32, 32), 64, 0, stream>>>(z0, w1, b1, z1, 1024, 1024, 768);
    gemm_relu_kernel<<<dim3(16, 32), 64, 0, stream>>>(z1, w2, b2, z2, 1024, 512, 1024);
    gemm_relu_kernel<<<dim3(4, 32), 64, 0, stream>>>(z2, w3, b3, z3, 1024, 128, 512);
    fc4_kernel<<<40, 256, 0, stream>>>(z3, w4, b4, out);
}